// Round 4
// baseline (8419.712 us; speedup 1.0000x reference)
//
#include <hip/hip_runtime.h>
#include <hip/hip_bf16.h>

// LSTM: B=64, D=32, H=512, T=1024. gates = [h,x] @ [W_hh;W_ih]^T + b_ih + b_hh
// Round 17: dual-publish h-exchange (protocol-free XCD locality).
// 128 blocks = 8 groups x 16 slices; group = blockIdx&7 (== XCD under RR
// placement). Producers store each 16B h-packet TWICE: sc0-only into a fast
// buffer (coherent at producer's L2) and sc0 sc1 into a slow buffer (device
// scope = validated R13 transport). Consumers poll fast with a BOUNDED retry
// (per-thread, per-quad); on timeout sticky-switch that quad to slow
// (unbounded poll, guaranteed visible -> deadlock impossible by construction;
// no discovery, no leader, no cross-block protocol). Freshness: 2-bit tag
// (d0/d3 bit16 = (t>>1)&1, d1 bit16 = (t>>2)&1, ring-8): any staleness gap
// mismatches at an earlier poll of the same line -> timeout -> sticky slow,
// so a stale tag-match is unreachable (visible versions are monotone).
// Per-block microkernel IDENTICAL to the validated R13 (512 thr, 8 waves,
// 4 units/wave, 16 gate rows, 51 MFMAs, Bh+Bl in VGPRs). LDS: 80 KB.

typedef unsigned short ushort_t;
typedef unsigned int   uint_t;
typedef unsigned long long u64_t;
typedef __attribute__((ext_vector_type(8))) short bf16x8;
typedef __attribute__((ext_vector_type(4))) float f32x4;
typedef __attribute__((ext_vector_type(4))) uint_t u32x4;

#define T_STEPS 1024
#define HID     512
#define KDIM    544   // 512 h + 32 x
#define NBLK    128   // 8 groups * 16 slices
#define NTHR    512

// per-buffer geometry: 2 parities * 8 groups * 128 waves * 16 packets * 16B
#define HX_GRP_BYTES   32768
#define HX_BYTES       (2 * 8 * HX_GRP_BYTES)  // 524288 per buffer
#define HX_U32         (HX_BYTES / 4)          // 131072

__device__ inline ushort_t f2bf(float x) {
    __hip_bfloat16 h = __float2bfloat16(x);
    return *(ushort_t*)&h;
}
__device__ inline float bf2f(ushort_t u) {
    __hip_bfloat16 h = *(__hip_bfloat16*)&u;
    return __bfloat162float(h);
}

__device__ inline f32x4 MFMA(bf16x8 a, bf16x8 b, f32x4 c) {
    return __builtin_amdgcn_mfma_f32_16x16x32_bf16(a, b, c, 0, 0, 0);
}

// device-scope 16B load/store (L1+L2 bypass, meets at Infinity Cache)
__device__ inline u32x4 cld16(const void* p) {
    u32x4 v;
    asm volatile("global_load_dwordx4 %0, %1, off sc0 sc1"
                 : "=v"(v) : "v"(p) : "memory");
    return v;
}
__device__ inline void cst16(void* p, u32x4 v) {
    asm volatile("global_store_dwordx4 %0, %1, off sc0 sc1"
                 :: "v"(p), "v"(v) : "memory");
}
// XCD-scope 16B load/store (L1 bypass only; coherent at the XCD's L2)
__device__ inline u32x4 cld16_l2(const void* p) {
    u32x4 v;
    asm volatile("global_load_dwordx4 %0, %1, off sc0"
                 : "=v"(v) : "v"(p) : "memory");
    return v;
}
__device__ inline void cst16_l2(void* p, u32x4 v) {
    asm volatile("global_store_dwordx4 %0, %1, off sc0"
                 :: "v"(p), "v"(v) : "memory");
}
__device__ inline void waitvm0() {
    asm volatile("s_waitcnt vmcnt(0)" ::: "memory");
}

__device__ inline bool tag_ok(u32x4 v, uint_t tb0, uint_t tb1) {
    return (((v[0] >> 16) & 1u) == tb0) & (((v[1] >> 16) & 1u) == tb1) &
           (((v[3] >> 16) & 1u) == tb0);
}

// is_tanh: tanh(v)=(1-e)/(1+e), e=2^(-2.885*v); sigmoid(v)=1/(1+e), e=2^(-1.4427*v)
__device__ inline float act_gate(float v, int is_tanh) {
    float vc = fminf(fmaxf(v, -43.f), 43.f);
    float kk = is_tanh ? -2.88539008f : -1.44269504f;
    float e  = __builtin_exp2f(vc * kk);
    float num = is_tanh ? (1.f - e) : 1.f;
    return num * __builtin_amdgcn_rcpf(1.f + e);
}

__device__ inline float sel4(int i, float a, float b, float c, float d) {
    return (i == 0) ? a : (i == 1) ? b : (i == 2) ? c : d;
}

// ---------- prep kernels ----------

__global__ void k_init(uint_t* hx32) {
    // grid 1024x256 covers BOTH buffers (fast + slow), 2*131072 u32.
    // init value ~0 (denormal bf16); tag bits (d-index mod 4: 0..3 all get
    // bit16=1) -> init reads as tag (1,1), first expected tags are (0,0) ->
    // mismatch at t=1 -> no ABA with init data.
    int i = blockIdx.x * 256 + threadIdx.x;
    hx32[i] = 0x00010000u;
}

__global__ void k_wcat(const float* __restrict__ wih, const float* __restrict__ whh,
                       ushort_t* __restrict__ wh, ushort_t* __restrict__ wl) {
    int r = blockIdx.x;                          // 2048 gate rows
    for (int k = threadIdx.x; k < KDIM; k += 256) {
        float w = (k < 512) ? whh[r * 512 + k] : wih[r * 32 + (k - 512)];
        ushort_t hh = f2bf(w);
        ushort_t ll = f2bf(w - bf2f(hh));
        wh[r * KDIM + k] = hh;
        wl[r * KDIM + k] = ll;
    }
}

// input (B=64, D=32, T=1024) fp32 -> xbuf[t][b][d] bf16 hi/lo
__global__ void k_xbuf(const float* __restrict__ in,
                       ushort_t* __restrict__ xh, ushort_t* __restrict__ xl) {
    __shared__ float tile[64][65];
    int bp = blockIdx.x >> 4;                    // batch pair 0..31
    int tt = blockIdx.x & 15;                    // t tile 0..15
    int t0 = tt * 64;
    int wv = threadIdx.x >> 6, l = threadIdx.x & 63;
    for (int r = wv * 16; r < wv * 16 + 16; r++) {
        int b = bp * 2 + (r >> 5), d = r & 31;
        tile[r][l] = in[(b * 32 + d) * 1024 + t0 + l];
    }
    __syncthreads();
    for (int i = 0; i < 16; i++) {
        int tl = wv * 16 + i;
        float v = tile[l][tl];
        ushort_t hh = f2bf(v);
        ushort_t ll = f2bf(v - bf2f(hh));
        int o = (t0 + tl) * 2048 + bp * 64 + l;  // = t*64*32 + b*32 + d
        xh[o] = hh;
        xl[o] = ll;
    }
}

// out[b][t] = conv_b + sum_s part[(g*16+s)*8 + bl][t]   (b = g*8+bl)
__global__ void k_reduce(const float* __restrict__ part, float* __restrict__ out,
                         const float* __restrict__ cvb) {
    int b = blockIdx.x >> 2;                     // 0..63
    int t = (blockIdx.x & 3) * 256 + threadIdx.x;
    int g = b >> 3, bl = b & 7;
    const float* p = part + ((size_t)(g * 128 + bl)) * 1024 + t;
    float sum = 0.f;
    #pragma unroll
    for (int s = 0; s < 16; s++) sum += p[(size_t)s * 8 * 1024];
    out[b * 1024 + t] = sum + cvb[0];
}

// ---------- main recurrent kernel ----------

__global__ __launch_bounds__(NTHR, 2) void k_lstm(
    const ushort_t* __restrict__ wh, const ushort_t* __restrict__ wlo,
    const ushort_t* __restrict__ xh, const ushort_t* __restrict__ xl,
    char* hx,
    const float* __restrict__ bih, const float* __restrict__ bhh,
    const float* __restrict__ convw, float* __restrict__ part)
{
    const int tid = threadIdx.x;
    const int w   = tid >> 6;          // wave 0..7 (unit nibble)
    const int l   = tid & 63;
    const int g   = blockIdx.x & 7;    // batch group 0..7 (== XCD under RR)
    const int s   = blockIdx.x >> 3;   // hidden slice 0..15 (32 units each)
    const int n   = l & 15;            // B-tile row within wave
    const int q   = l >> 4;            // quad
    const int gtn = n >> 2;            // gate 0..3 (i,f,g,o)
    const int u   = n & 3;             // unit within wave
    const int j   = s * 32 + w * 4 + u;// hidden unit 0..511
    const int row = gtn * HID + j;     // gate row 0..2047
    const int b0  = g * 8;             // 8 real batches per group
    const int wg  = s * 8 + w;         // producing-wave id in group, 0..127

    char* hxF = hx;                    // fast buffer (sc0-only, L2 scope)
    char* hxS = hx + HX_BYTES;         // slow buffer (sc0 sc1, device scope)

    __shared__ u64_t hs[2][4096];              // staged h, dbuf (64 KB)
    __shared__ float projsh[8][16][32];        // projection partials (16 KB)

    // W_hi AND W_lo fragments in registers: 17 K-chunks each
    bf16x8 Bh[17], Bl[17];
    #pragma unroll
    for (int c = 0; c < 17; c++) {
        Bh[c] = *(const bf16x8*)(wh  + row * KDIM + c * 32 + q * 8);
        Bl[c] = *(const bf16x8*)(wlo + row * KDIM + c * 32 + q * 8);
    }

    const float bias = bih[row] + bhh[row];
    const float cw   = convw[j];
    float cst[4] = {0.f, 0.f, 0.f, 0.f};

    // staging mapping (unchanged from R13): packet p = k*512+tid (k=0..3)
    // -> wg' = p>>4, m = p&15; c = k*4 + (hi5>>3), q = (hi5>>1)&3, d = hi5&1
    const int m16 = tid & 15;
    const int hi5 = tid >> 4;
    const int sq  = (hi5 >> 1) & 3, sd = hi5 & 1, sc0v = hi5 >> 3;

    // per-thread, per-quad sticky: bit k set -> quad k polls the slow buffer
    uint_t slowmask = 0;

    __syncthreads();

    union frag { u64_t d[2]; bf16x8 v; };

    for (int t = 0; t < T_STEPS; t++) {
        // ---- stage: 4 coherent 16B loads issued FIRST (longest latency) ----
        const char* srcF = hxF + (size_t)((t & 1) * 8 + g) * HX_GRP_BYTES + tid * 16;
        const char* srcS = srcF + HX_BYTES;
        u32x4 hv[4];
        #pragma unroll
        for (int k = 0; k < 4; k++) {
            hv[k] = (slowmask & (1u << k)) ? cld16(srcS + k * 8192)
                                           : cld16_l2(srcF + k * 8192);
        }

        frag Ax, Lx;
        // x fragment (no recurrence dependence); rows 8..15 duplicate 0..7
        {
            int xo = (t * 64 + b0 + (n & 7)) * 32 + q * 8;
            Ax.v = *(const bf16x8*)(xh + xo);
            Lx.v = *(const bf16x8*)(xl + xo);
        }

        waitvm0();
        if (t > 0) {
            const uint_t tb0 = ((uint_t)(t - 1) >> 1) & 1u;
            const uint_t tb1 = ((uint_t)(t - 1) >> 2) & 1u;
            int rounds = 0;
            for (;;) {
                bool any = false;
                #pragma unroll
                for (int k = 0; k < 4; k++) {
                    if (!tag_ok(hv[k], tb0, tb1)) {
                        any = true;
                        hv[k] = (slowmask & (1u << k))
                                  ? cld16(srcS + k * 8192)
                                  : cld16_l2(srcF + k * 8192);
                    }
                }
                if (!any) break;
                // bounded fast phase: after 400 failed rounds, sticky-switch
                // still-pending quads to the device-scope slow buffer
                // (guaranteed visible -> loop always terminates).
                if (++rounds == 400) {
                    #pragma unroll
                    for (int k = 0; k < 4; k++)
                        if (!tag_ok(hv[k], tb0, tb1)) slowmask |= 1u << k;
                }
                __builtin_amdgcn_s_sleep(1);   // backoff: decongest fabric
                waitvm0();
            }
        }
        // deinterleave dwords (hi,lo)x4 units -> hi x4, lo x4; into LDS dbuf
        {
            const int buf = t & 1;
            #pragma unroll
            for (int k = 0; k < 4; k++) {
                uint_t I0 = hv[k][0], I1 = hv[k][1];
                uint_t I2 = hv[k][2], I3 = hv[k][3];
                uint_t hA = __builtin_amdgcn_perm(I1, I0, 0x05040100u);
                uint_t hB = __builtin_amdgcn_perm(I3, I2, 0x05040100u);
                uint_t lA = __builtin_amdgcn_perm(I1, I0, 0x07060302u);
                uint_t lB = __builtin_amdgcn_perm(I3, I2, 0x07060302u);
                int c  = k * 4 + sc0v;
                int li = ((c * 4 + sq) * 16 + m16) * 2 + sd;
                hs[buf][li]        = (u64_t)hA | ((u64_t)hB << 32);
                hs[buf][li + 2048] = (u64_t)lA | ((u64_t)lB << 32);
            }
        }
        __syncthreads();   // the only per-step barrier

        // fragments from LDS: contiguous 16B b128 reads; B operands in VGPRs
        const int buf = t & 1;
        f32x4 a0 = {0,0,0,0}, a1 = {0,0,0,0}, a2 = {0,0,0,0},
              a3 = {0,0,0,0}, a4 = {0,0,0,0}, a5 = {0,0,0,0};
        #pragma unroll
        for (int c = 0; c < 16; c++) {
            frag Ah, Al;
            int li = ((c * 4 + q) * 16 + n) * 2;
            Ah.v = *(const bf16x8*)&hs[buf][li];
            Al.v = *(const bf16x8*)&hs[buf][li + 2048];
            if (c & 1) {
                a1 = MFMA(Ah.v, Bh[c], a1);
                a3 = MFMA(Ah.v, Bl[c], a3);
                a5 = MFMA(Al.v, Bh[c], a5);
            } else {
                a0 = MFMA(Ah.v, Bh[c], a0);
                a2 = MFMA(Ah.v, Bl[c], a2);
                a4 = MFMA(Al.v, Bh[c], a4);
            }
        }
        {   // x chunk (c=16)
            a0 = MFMA(Ax.v, Bh[16], a0);
            a2 = MFMA(Ax.v, Bl[16], a2);
            a4 = MFMA(Lx.v, Bh[16], a4);
        }
        f32x4 D = (a0 + a1) + (a2 + a3) + (a4 + a5);

        // epilogue: lane holds gate row n for batches m=q*4+r.
        // pack (hi,lo)x4 units into one 16B packet per r; tags: d0/d3 bit16 =
        // (t>>1)&1, d1 bit16 = (t>>2)&1 (2-bit tag, ring-8). Dual-publish.
        char* dstF = hxF + (size_t)((((t + 1) & 1) * 8 + g) * 128 + wg) * 256;
        const uint_t ptb0 = ((uint_t)((t >> 1) & 1)) << 16;
        const uint_t ptb1 = ((uint_t)((t >> 2) & 1)) << 16;
        float pr[4];
        #pragma unroll
        for (int r = 0; r < 4; r++) {
            float v   = D[r] + bias;
            float act = act_gate(v, gtn == 2);
            float v4  = __shfl_xor(act, 4);
            float v8  = __shfl_xor(act, 8);
            float v12 = __shfl_xor(v4, 8);
            // gate G lives at arr[gtn ^ G]; arr = {act, v4, v8, v12}
            float iv = sel4(gtn,     act, v4, v8, v12);
            float fv = sel4(gtn ^ 1, act, v4, v8, v12);
            float gv = sel4(gtn ^ 2, act, v4, v8, v12);
            float ov = sel4(gtn ^ 3, act, v4, v8, v12);
            float cc = fv * cst[r] + iv * gv;
            cst[r] = cc;
            float th = act_gate(cc, 1);
            float h  = ov * th;
            pr[r] = cw * h;
            ushort_t hb = f2bf(h);
            uint_t hvp = (uint_t)hb;
            uint_t lvp = (uint_t)f2bf(h - bf2f(hb));
            uint_t ivp = hvp | (lvp << 16);                 // (hi,lo) unit u
            uint_t ip1 = (uint_t)__shfl_xor((int)ivp, 1);   // unit u^1
            uint_t bl2 = (uint_t)__shfl_xor((int)ivp, 2);   // unit u^2
            uint_t bh2 = (uint_t)__shfl_xor((int)ip1, 2);   // unit u^3
            if (n == 0) {
                u32x4 pkt;
                pkt[0] = (ivp & ~0x10000u) | ptb0;
                pkt[1] = (ip1 & ~0x10000u) | ptb1;
                pkt[2] = bl2;
                pkt[3] = (bh2 & ~0x10000u) | ptb0;
                cst16_l2(dstF + (q * 4 + r) * 16, pkt);           // fast
                cst16   (dstF + HX_BYTES + (q * 4 + r) * 16, pkt);// slow
            }
        }
        // NO drain, NO flag: tagged data IS the publication.

        // projection partial (off critical path)
        #pragma unroll
        for (int r = 0; r < 4; r++) {
            pr[r] += __shfl_xor(pr[r], 1);
            pr[r] += __shfl_xor(pr[r], 2);
            if (n == 0) projsh[w][q * 4 + r][t & 31] = pr[r];
        }
        if ((t & 31) == 31) {
            __syncthreads();
            // 256 entries (8 real batches x 32 steps), one per thread
            int b = tid >> 5, tl = tid & 31;
            if (b < 8) {
                float v = ((projsh[0][b][tl] + projsh[1][b][tl]) +
                           (projsh[2][b][tl] + projsh[3][b][tl])) +
                          ((projsh[4][b][tl] + projsh[5][b][tl]) +
                           (projsh[6][b][tl] + projsh[7][b][tl]));
                float* dpt = part + (size_t)((g * 16 + s) * 8 + b) * 1024 + (t - 31);
                __builtin_nontemporal_store(v, dpt + tl);
            }
            __syncthreads();
        }
    }
}

extern "C" void kernel_launch(void* const* d_in, const int* in_sizes, int n_in,
                              void* d_out, int out_size, void* d_ws, size_t ws_size,
                              hipStream_t stream) {
    const float* in  = (const float*)d_in[0];
    const float* Wih = (const float*)d_in[1];
    const float* Whh = (const float*)d_in[2];
    const float* bih = (const float*)d_in[3];
    const float* bhh = (const float*)d_in[4];
    const float* cvw = (const float*)d_in[5];
    const float* cvb = (const float*)d_in[6];
    float* out = (float*)d_out;

    char* ws = (char*)d_ws;
    ushort_t* wh  = (ushort_t*)ws; ws += (size_t)2048 * KDIM * 2;      // 2,228,224
    ushort_t* wl  = (ushort_t*)ws; ws += (size_t)2048 * KDIM * 2;
    ushort_t* xh  = (ushort_t*)ws; ws += (size_t)1024 * 64 * 32 * 2;   // 4,194,304
    ushort_t* xl  = (ushort_t*)ws; ws += (size_t)1024 * 64 * 32 * 2;
    char*     hx  = ws;            ws += (size_t)2 * HX_BYTES;         // 1,048,576
    float*    pp  = (float*)ws;    ws += (size_t)8 * 16 * 8 * 1024 * 4;// 4,194,304
    // total ~18.1 MB of ws

    k_init<<<1024, 256, 0, stream>>>((uint_t*)hx);
    k_wcat<<<2048, 256, 0, stream>>>(Wih, Whh, wh, wl);
    k_xbuf<<<512, 256, 0, stream>>>(in, xh, xl);
    k_lstm<<<NBLK, NTHR, 0, stream>>>(wh, wl, xh, xl, hx,
                                      bih, bhh, cvw, pp);
    k_reduce<<<256, 256, 0, stream>>>(pp, out, cvb);
}

// Round 5
// 4039.694 us; speedup vs baseline: 2.0842x; 2.0842x over previous
//
#include <hip/hip_runtime.h>
#include <hip/hip_bf16.h>

// LSTM: B=64, D=32, H=512, T=1024. gates = [h,x] @ [W_hh;W_ih]^T + b_ih + b_hh
// Round 18: R13 structure restored (64 blocks = 4 groups x 16 slices, 512 thr,
// 8 waves, 4 units/wave, 16 gate rows, 51 MFMAs, Bh+Bl in VGPRs, device-scope
// sc0sc1 data-as-flag packets, tag bit16 ring-2) + ONE delta: early-probe
// queue reordering. vmcnt retires FIFO, so R13's top-of-step waitvm0 had to
// drain the previous step's 4 sc0sc1 packet stores (IC write-ack ~600-1000cy)
// before the tag check could run. Now: after the MFMA reduce of step t we
// issue x-loads(t+1) then h-probe loads(t+1) BEFORE the packet stores; the
// next top waits s_waitcnt vmcnt(4), retiring exactly 2 x-loads + 4 h-loads
// while stores stay in flight. Retry loop unchanged (waitvm0; acks done by
// then). Own-packet early probes may read pre-store data -> tag mismatch ->
// one retry (16B-atomic dwordx4 + 1-bit ring-2 tag make torn/stale reads
// detectable, same invariants R13 already relied on). LDS: 80 KB.

typedef unsigned short ushort_t;
typedef unsigned int   uint_t;
typedef unsigned long long u64_t;
typedef __attribute__((ext_vector_type(8))) short bf16x8;
typedef __attribute__((ext_vector_type(4))) float f32x4;
typedef __attribute__((ext_vector_type(4))) uint_t u32x4;

#define T_STEPS 1024
#define HID     512
#define KDIM    544   // 512 h + 32 x
#define NBLK    64    // 4 groups * 16 slices
#define NTHR    512

__device__ inline ushort_t f2bf(float x) {
    __hip_bfloat16 h = __float2bfloat16(x);
    return *(ushort_t*)&h;
}
__device__ inline float bf2f(ushort_t u) {
    __hip_bfloat16 h = *(__hip_bfloat16*)&u;
    return __bfloat162float(h);
}

__device__ inline f32x4 MFMA(bf16x8 a, bf16x8 b, f32x4 c) {
    return __builtin_amdgcn_mfma_f32_16x16x32_bf16(a, b, c, 0, 0, 0);
}

// coherent 16B load/store (L1+L2 bypass, meets at Infinity Cache)
__device__ inline u32x4 cld16(const void* p) {
    u32x4 v;
    asm volatile("global_load_dwordx4 %0, %1, off sc0 sc1"
                 : "=v"(v) : "v"(p) : "memory");
    return v;
}
__device__ inline void cst16(void* p, u32x4 v) {
    asm volatile("global_store_dwordx4 %0, %1, off sc0 sc1"
                 :: "v"(p), "v"(v) : "memory");
}
__device__ inline void waitvm0() {
    asm volatile("s_waitcnt vmcnt(0)" ::: "memory");
}
__device__ inline void waitvm4() {
    asm volatile("s_waitcnt vmcnt(4)" ::: "memory");
}

// is_tanh: tanh(v)=(1-e)/(1+e), e=2^(-2.885*v); sigmoid(v)=1/(1+e), e=2^(-1.4427*v)
__device__ inline float act_gate(float v, int is_tanh) {
    float vc = fminf(fmaxf(v, -43.f), 43.f);
    float kk = is_tanh ? -2.88539008f : -1.44269504f;
    float e  = __builtin_exp2f(vc * kk);
    float num = is_tanh ? (1.f - e) : 1.f;
    return num * __builtin_amdgcn_rcpf(1.f + e);
}

__device__ inline float sel4(int i, float a, float b, float c, float d) {
    return (i == 0) ? a : (i == 1) ? b : (i == 2) ? c : d;
}

// ---------- prep kernels ----------

__global__ void k_init(uint_t* hx32) {
    int i = blockIdx.x * 256 + threadIdx.x;      // grid 256x256 = 65536
    // init h ring: value ~0 (denormal bf16), tag bit16 = 1 (differs from tag 0
    // expected at t=1/t=2) -> no ABA with init data.
    hx32[i] = 0x00010000u;                       // 2*4*128*16 x 16B = 65536 u32
}

__global__ void k_wcat(const float* __restrict__ wih, const float* __restrict__ whh,
                       ushort_t* __restrict__ wh, ushort_t* __restrict__ wl) {
    int r = blockIdx.x;                          // 2048 gate rows
    for (int k = threadIdx.x; k < KDIM; k += 256) {
        float w = (k < 512) ? whh[r * 512 + k] : wih[r * 32 + (k - 512)];
        ushort_t hh = f2bf(w);
        ushort_t ll = f2bf(w - bf2f(hh));
        wh[r * KDIM + k] = hh;
        wl[r * KDIM + k] = ll;
    }
}

// input (B=64, D=32, T=1024) fp32 -> xbuf[t][b][d] bf16 hi/lo
__global__ void k_xbuf(const float* __restrict__ in,
                       ushort_t* __restrict__ xh, ushort_t* __restrict__ xl) {
    __shared__ float tile[64][65];
    int bp = blockIdx.x >> 4;                    // batch pair 0..31
    int tt = blockIdx.x & 15;                    // t tile 0..15
    int t0 = tt * 64;
    int wv = threadIdx.x >> 6, l = threadIdx.x & 63;
    for (int r = wv * 16; r < wv * 16 + 16; r++) {
        int b = bp * 2 + (r >> 5), d = r & 31;
        tile[r][l] = in[(b * 32 + d) * 1024 + t0 + l];
    }
    __syncthreads();
    for (int i = 0; i < 16; i++) {
        int tl = wv * 16 + i;
        float v = tile[l][tl];
        ushort_t hh = f2bf(v);
        ushort_t ll = f2bf(v - bf2f(hh));
        int o = (t0 + tl) * 2048 + bp * 64 + l;  // = t*64*32 + b*32 + d
        xh[o] = hh;
        xl[o] = ll;
    }
}

// out[b][t] = conv_b + sum_s part[(g*16+s)*16 + bl][t]   (b = g*16+bl)
__global__ void k_reduce(const float* __restrict__ part, float* __restrict__ out,
                         const float* __restrict__ cvb) {
    int b = blockIdx.x >> 2;                     // 0..63
    int t = (blockIdx.x & 3) * 256 + threadIdx.x;
    int g = b >> 4, bl = b & 15;
    const float* p = part + ((size_t)(g * 16 * 16 + bl)) * 1024 + t;
    float sum = 0.f;
    #pragma unroll
    for (int s = 0; s < 16; s++) sum += p[(size_t)s * 16 * 1024];
    out[b * 1024 + t] = sum + cvb[0];
}

// ---------- main recurrent kernel ----------

__global__ __launch_bounds__(NTHR, 2) void k_lstm(
    const ushort_t* __restrict__ wh, const ushort_t* __restrict__ wlo,
    const ushort_t* __restrict__ xh, const ushort_t* __restrict__ xl,
    char* hx,
    const float* __restrict__ bih, const float* __restrict__ bhh,
    const float* __restrict__ convw, float* __restrict__ part)
{
    const int tid = threadIdx.x;
    const int w   = tid >> 6;          // wave 0..7 (unit nibble)
    const int l   = tid & 63;
    const int g   = blockIdx.x >> 4;   // batch group 0..3
    const int s   = blockIdx.x & 15;   // hidden slice 0..15 (32 units each)
    const int n   = l & 15;            // B-tile row within wave
    const int q   = l >> 4;            // quad
    const int gtn = n >> 2;            // gate 0..3 (i,f,g,o)
    const int u   = n & 3;             // unit within wave
    const int j   = s * 32 + w * 4 + u;// hidden unit 0..511
    const int row = gtn * HID + j;     // gate row 0..2047
    const int b0  = g * 16;
    const int wg  = s * 8 + w;         // producing-wave id in group, 0..127

    __shared__ u64_t hs[2][4096];              // staged h, dbuf (64 KB)
    __shared__ float projsh[8][16][32];        // projection partials (16 KB)

    // W_hi AND W_lo fragments in registers: 17 K-chunks each
    bf16x8 Bh[17], Bl[17];
    #pragma unroll
    for (int c = 0; c < 17; c++) {
        Bh[c] = *(const bf16x8*)(wh  + row * KDIM + c * 32 + q * 8);
        Bl[c] = *(const bf16x8*)(wlo + row * KDIM + c * 32 + q * 8);
    }

    const float bias = bih[row] + bhh[row];
    const float cw   = convw[j];
    float cst[4] = {0.f, 0.f, 0.f, 0.f};

    // staging mapping: packet p = k*512+tid (k=0..3) -> wg' = p>>4, m = p&15
    // wg' = k*32 + hi5 (hi5 = tid>>4); c = k*4 + (hi5>>3), q = (hi5>>1)&3,
    // d = hi5&1, n = m
    const int m16 = tid & 15;
    const int hi5 = tid >> 4;
    const int sq  = (hi5 >> 1) & 3, sd = hi5 & 1, sc0v = hi5 >> 3;

    __syncthreads();

    union frag { u64_t d[2]; bf16x8 v; };
    u32x4 hv[4];
    frag Ax, Lx;

    // ---- prologue: issue x-loads(t=0) then h-probe loads(t=0) ----
    {
        int xo = (0 * 64 + b0 + n) * 32 + q * 8;
        Ax.v = *(const bf16x8*)(xh + xo);
        Lx.v = *(const bf16x8*)(xl + xo);
        const char* srcB0 = hx + (size_t)g * 32768 + tid * 16;  // parity 0
        #pragma unroll
        for (int k = 0; k < 4; k++) hv[k] = cld16(srcB0 + k * 8192);
    }

    for (int t = 0; t < T_STEPS; t++) {
        const char* srcB = hx + (size_t)(((t & 1) * 4 + g)) * 32768 + tid * 16;

        // ---- wait: retire ONLY the 2 x-loads + 4 h-probes (oldest in queue);
        //      the 4 packet stores from step t-1 stay in flight ----
        if (t == 0) waitvm0();
        else        waitvm4();

        if (t > 0) {
            const uint_t exp = ((uint_t)(((t - 1) >> 1) & 1)) << 16;
            for (;;) {
                bool ok = true;
                #pragma unroll
                for (int k = 0; k < 4; k++) {
                    if (((hv[k][0] & 0x10000u) != exp) ||
                        ((hv[k][3] & 0x10000u) != exp)) {
                        hv[k] = cld16(srcB + k * 8192);
                        ok = false;
                    }
                }
                if (ok) break;
                __builtin_amdgcn_s_sleep(1);   // backoff: decongest fabric
                waitvm0();                     // stores ack'd by now
            }
        }
        // deinterleave dwords (hi,lo)x4 units -> hi x4, lo x4; into LDS dbuf
        {
            const int buf = t & 1;
            #pragma unroll
            for (int k = 0; k < 4; k++) {
                uint_t I0 = hv[k][0], I1 = hv[k][1];
                uint_t I2 = hv[k][2], I3 = hv[k][3];
                uint_t hA = __builtin_amdgcn_perm(I1, I0, 0x05040100u);
                uint_t hB = __builtin_amdgcn_perm(I3, I2, 0x05040100u);
                uint_t lA = __builtin_amdgcn_perm(I1, I0, 0x07060302u);
                uint_t lB = __builtin_amdgcn_perm(I3, I2, 0x07060302u);
                int c  = k * 4 + sc0v;
                int li = ((c * 4 + sq) * 16 + m16) * 2 + sd;
                hs[buf][li]        = (u64_t)hA | ((u64_t)hB << 32);
                hs[buf][li + 2048] = (u64_t)lA | ((u64_t)lB << 32);
            }
        }
        __syncthreads();   // the only per-step barrier

        // fragments from LDS: contiguous 16B b128 reads; B operands in VGPRs
        const int buf = t & 1;
        f32x4 a0 = {0,0,0,0}, a1 = {0,0,0,0}, a2 = {0,0,0,0},
              a3 = {0,0,0,0}, a4 = {0,0,0,0}, a5 = {0,0,0,0};
        #pragma unroll
        for (int c = 0; c < 16; c++) {
            frag Ah, Al;
            int li = ((c * 4 + q) * 16 + n) * 2;
            Ah.v = *(const bf16x8*)&hs[buf][li];
            Al.v = *(const bf16x8*)&hs[buf][li + 2048];
            if (c & 1) {
                a1 = MFMA(Ah.v, Bh[c], a1);
                a3 = MFMA(Ah.v, Bl[c], a3);
                a5 = MFMA(Al.v, Bh[c], a5);
            } else {
                a0 = MFMA(Ah.v, Bh[c], a0);
                a2 = MFMA(Ah.v, Bl[c], a2);
                a4 = MFMA(Al.v, Bh[c], a4);
            }
        }
        {   // x chunk (c=16)
            a0 = MFMA(Ax.v, Bh[16], a0);
            a2 = MFMA(Ax.v, Bl[16], a2);
            a4 = MFMA(Lx.v, Bh[16], a4);
        }
        f32x4 D = (a0 + a1) + (a2 + a3) + (a4 + a5);

        // ---- early probes for t+1: x-loads then h-loads, issued BEFORE the
        //      packet stores so they are OLDEST in the vm queue ----
        if (t + 1 < T_STEPS) {
            int xo = ((t + 1) * 64 + b0 + n) * 32 + q * 8;
            Ax.v = *(const bf16x8*)(xh + xo);
            Lx.v = *(const bf16x8*)(xl + xo);
            const char* srcN = hx + (size_t)((((t + 1) & 1) * 4 + g)) * 32768 + tid * 16;
            #pragma unroll
            for (int k = 0; k < 4; k++) hv[k] = cld16(srcN + k * 8192);
        }

        // epilogue: lane holds gate row n for batches m=q*4+r.
        // pack (hi,lo)x4 units into one 16B packet per r, tag d0 & d3.
        char* dstB = hx + (size_t)((((t + 1) & 1) * 4 + g) * 128 + wg) * 256;
        const uint_t tag32 = ((uint_t)((t >> 1) & 1)) << 16;
        float pr[4];
        #pragma unroll
        for (int r = 0; r < 4; r++) {
            float v   = D[r] + bias;
            float act = act_gate(v, gtn == 2);
            float v4  = __shfl_xor(act, 4);
            float v8  = __shfl_xor(act, 8);
            float v12 = __shfl_xor(v4, 8);
            // gate G lives at arr[gtn ^ G]; arr = {act, v4, v8, v12}
            float iv = sel4(gtn,     act, v4, v8, v12);
            float fv = sel4(gtn ^ 1, act, v4, v8, v12);
            float gv = sel4(gtn ^ 2, act, v4, v8, v12);
            float ov = sel4(gtn ^ 3, act, v4, v8, v12);
            float cc = fv * cst[r] + iv * gv;
            cst[r] = cc;
            float th = act_gate(cc, 1);
            float h  = ov * th;
            pr[r] = cw * h;
            ushort_t hb = f2bf(h);
            uint_t hvp = (uint_t)hb;
            uint_t lvp = (uint_t)f2bf(h - bf2f(hb));
            uint_t ivp = hvp | (lvp << 16);                 // (hi,lo) unit u
            uint_t ip1 = (uint_t)__shfl_xor((int)ivp, 1);   // unit u^1
            uint_t bl2 = (uint_t)__shfl_xor((int)ivp, 2);   // unit u^2
            uint_t bh2 = (uint_t)__shfl_xor((int)ip1, 2);   // unit u^3
            if (n == 0) {
                u32x4 pkt;
                pkt[0] = (ivp & ~0x10000u) | tag32;
                pkt[1] = ip1;
                pkt[2] = bl2;
                pkt[3] = (bh2 & ~0x10000u) | tag32;
                cst16(dstB + (q * 4 + r) * 16, pkt);
            }
        }
        // NO drain, NO flag: tagged data IS the publication.

        // projection partial (off critical path)
        #pragma unroll
        for (int r = 0; r < 4; r++) {
            pr[r] += __shfl_xor(pr[r], 1);
            pr[r] += __shfl_xor(pr[r], 2);
            if (n == 0) projsh[w][q * 4 + r][t & 31] = pr[r];
        }
        if ((t & 31) == 31) {
            __syncthreads();
            // 512 entries (16 batches x 32 steps), one per thread
            int b = tid >> 5, tl = tid & 31;
            float v = ((projsh[0][b][tl] + projsh[1][b][tl]) +
                       (projsh[2][b][tl] + projsh[3][b][tl])) +
                      ((projsh[4][b][tl] + projsh[5][b][tl]) +
                       (projsh[6][b][tl] + projsh[7][b][tl]));
            float* dpt = part + (size_t)((g * 16 + s) * 16 + b) * 1024 + (t - 31);
            __builtin_nontemporal_store(v, dpt + tl);
            __syncthreads();
        }
    }
}

extern "C" void kernel_launch(void* const* d_in, const int* in_sizes, int n_in,
                              void* d_out, int out_size, void* d_ws, size_t ws_size,
                              hipStream_t stream) {
    const float* in  = (const float*)d_in[0];
    const float* Wih = (const float*)d_in[1];
    const float* Whh = (const float*)d_in[2];
    const float* bih = (const float*)d_in[3];
    const float* bhh = (const float*)d_in[4];
    const float* cvw = (const float*)d_in[5];
    const float* cvb = (const float*)d_in[6];
    float* out = (float*)d_out;

    char* ws = (char*)d_ws;
    ushort_t* wh  = (ushort_t*)ws; ws += (size_t)2048 * KDIM * 2;      // 2,228,224
    ushort_t* wl  = (ushort_t*)ws; ws += (size_t)2048 * KDIM * 2;
    ushort_t* xh  = (ushort_t*)ws; ws += (size_t)1024 * 64 * 32 * 2;   // 4,194,304
    ushort_t* xl  = (ushort_t*)ws; ws += (size_t)1024 * 64 * 32 * 2;
    char*     hx  = ws;            ws += (size_t)2 * 4 * 128 * 16 * 16;// 262,144
    float*    pp  = (float*)ws;    ws += (size_t)64 * 16 * 1024 * 4;   // 4,194,304
    // total ~17.3 MB of ws

    k_init<<<256, 256, 0, stream>>>((uint_t*)hx);
    k_wcat<<<2048, 256, 0, stream>>>(Wih, Whh, wh, wl);
    k_xbuf<<<512, 256, 0, stream>>>(in, xh, xl);
    k_lstm<<<NBLK, NTHR, 0, stream>>>(wh, wl, xh, xl, hx,
                                      bih, bhh, cvw, pp);
    k_reduce<<<256, 256, 0, stream>>>(pp, out, cvb);
}

// Round 6
// 3060.666 us; speedup vs baseline: 2.7509x; 1.3199x over previous
//
#include <hip/hip_runtime.h>
#include <hip/hip_bf16.h>

// LSTM: B=64, D=32, H=512, T=1024. gates = [h,x] @ [W_hh;W_ih]^T + b_ih + b_hh
// Round 19: R13 transport + OPERAND-SWAPPED MFMA epilogue. D = W·h^T instead
// of h·W^T: A/B fragment layouts are mutually transposed (outer idx lane&15,
// k=(lane>>4)*8+e for both), so per-lane fragment DATA is identical — LDS
// staging/reads unchanged; only the weight-row formula changes (16-row tile
// ordered unit-major: row = (n&3)*512 + s*32 + w*4 + (n>>2)). Result: lane
// (q,n) holds ALL 4 gates (i,f,g,o) of unit j=s*32+w*4+q for batch n in its
// 4 acc regs -> epilogue is lane-local: 0 shfl for gate exchange (was 12),
// 0 shfl for packing (was 12; every lane stores its own 4B word, one
// coalesced dword store per wave), 2 shfl for projection (was 8). ~35 ->
// ~2 DS-pipe shuffles/thread/step (~2000cy/CU/step of LDS-pipe freed).
// Every 4B word self-tagged (bit16 = (t>>1)&1, lo-LSB clobber ~2^-17):
// consumer checks all 4 words -> torn packets impossible (stronger than
// R13's d0/d3 check). Transport/poll/tags/staging otherwise IDENTICAL to
// the validated R13 (64 blocks = 4 groups x 16 slices, 512 thr, 51 MFMAs,
// Bh+Bl in VGPRs, sc0sc1 data-as-flag, ring-2). LDS: 80 KB.

typedef unsigned short ushort_t;
typedef unsigned int   uint_t;
typedef unsigned long long u64_t;
typedef __attribute__((ext_vector_type(8))) short bf16x8;
typedef __attribute__((ext_vector_type(4))) float f32x4;
typedef __attribute__((ext_vector_type(4))) uint_t u32x4;

#define T_STEPS 1024
#define HID     512
#define KDIM    544   // 512 h + 32 x
#define NBLK    64    // 4 groups * 16 slices
#define NTHR    512

__device__ inline ushort_t f2bf(float x) {
    __hip_bfloat16 h = __float2bfloat16(x);
    return *(ushort_t*)&h;
}
__device__ inline float bf2f(ushort_t u) {
    __hip_bfloat16 h = *(__hip_bfloat16*)&u;
    return __bfloat162float(h);
}

__device__ inline f32x4 MFMA(bf16x8 a, bf16x8 b, f32x4 c) {
    return __builtin_amdgcn_mfma_f32_16x16x32_bf16(a, b, c, 0, 0, 0);
}

// coherent 16B load / 4B store (L1+L2 bypass, meets at Infinity Cache)
__device__ inline u32x4 cld16(const void* p) {
    u32x4 v;
    asm volatile("global_load_dwordx4 %0, %1, off sc0 sc1"
                 : "=v"(v) : "v"(p) : "memory");
    return v;
}
__device__ inline void cst4(void* p, uint_t v) {
    asm volatile("global_store_dword %0, %1, off sc0 sc1"
                 :: "v"(p), "v"(v) : "memory");
}
__device__ inline void waitvm0() {
    asm volatile("s_waitcnt vmcnt(0)" ::: "memory");
}

// is_tanh: tanh(v)=(1-e)/(1+e), e=2^(-2.885*v); sigmoid(v)=1/(1+e), e=2^(-1.4427*v)
__device__ inline float act_gate(float v, int is_tanh) {
    float vc = fminf(fmaxf(v, -43.f), 43.f);
    float kk = is_tanh ? -2.88539008f : -1.44269504f;
    float e  = __builtin_exp2f(vc * kk);
    float num = is_tanh ? (1.f - e) : 1.f;
    return num * __builtin_amdgcn_rcpf(1.f + e);
}

// ---------- prep kernels ----------

__global__ void k_init(uint_t* hx32) {
    int i = blockIdx.x * 256 + threadIdx.x;      // grid 256x256 = 65536
    // init h ring: value ~0 (denormal bf16), tag bit16 = 1 (differs from tag 0
    // expected at t=1/t=2) -> no ABA with init data.
    hx32[i] = 0x00010000u;                       // 2*4*128*16 x 16B = 65536 u32
}

__global__ void k_wcat(const float* __restrict__ wih, const float* __restrict__ whh,
                       ushort_t* __restrict__ wh, ushort_t* __restrict__ wl) {
    int r = blockIdx.x;                          // 2048 gate rows
    for (int k = threadIdx.x; k < KDIM; k += 256) {
        float w = (k < 512) ? whh[r * 512 + k] : wih[r * 32 + (k - 512)];
        ushort_t hh = f2bf(w);
        ushort_t ll = f2bf(w - bf2f(hh));
        wh[r * KDIM + k] = hh;
        wl[r * KDIM + k] = ll;
    }
}

// input (B=64, D=32, T=1024) fp32 -> xbuf[t][b][d] bf16 hi/lo
__global__ void k_xbuf(const float* __restrict__ in,
                       ushort_t* __restrict__ xh, ushort_t* __restrict__ xl) {
    __shared__ float tile[64][65];
    int bp = blockIdx.x >> 4;                    // batch pair 0..31
    int tt = blockIdx.x & 15;                    // t tile 0..15
    int t0 = tt * 64;
    int wv = threadIdx.x >> 6, l = threadIdx.x & 63;
    for (int r = wv * 16; r < wv * 16 + 16; r++) {
        int b = bp * 2 + (r >> 5), d = r & 31;
        tile[r][l] = in[(b * 32 + d) * 1024 + t0 + l];
    }
    __syncthreads();
    for (int i = 0; i < 16; i++) {
        int tl = wv * 16 + i;
        float v = tile[l][tl];
        ushort_t hh = f2bf(v);
        ushort_t ll = f2bf(v - bf2f(hh));
        int o = (t0 + tl) * 2048 + bp * 64 + l;  // = t*64*32 + b*32 + d
        xh[o] = hh;
        xl[o] = ll;
    }
}

// out[b][t] = conv_b + sum_s part[(g*16+s)*16 + bl][t]   (b = g*16+bl)
__global__ void k_reduce(const float* __restrict__ part, float* __restrict__ out,
                         const float* __restrict__ cvb) {
    int b = blockIdx.x >> 2;                     // 0..63
    int t = (blockIdx.x & 3) * 256 + threadIdx.x;
    int g = b >> 4, bl = b & 15;
    const float* p = part + ((size_t)(g * 16 * 16 + bl)) * 1024 + t;
    float sum = 0.f;
    #pragma unroll
    for (int s = 0; s < 16; s++) sum += p[(size_t)s * 16 * 1024];
    out[b * 1024 + t] = sum + cvb[0];
}

// ---------- main recurrent kernel ----------

__global__ __launch_bounds__(NTHR, 2) void k_lstm(
    const ushort_t* __restrict__ wh, const ushort_t* __restrict__ wlo,
    const ushort_t* __restrict__ xh, const ushort_t* __restrict__ xl,
    char* hx,
    const float* __restrict__ bih, const float* __restrict__ bhh,
    const float* __restrict__ convw, float* __restrict__ part)
{
    const int tid = threadIdx.x;
    const int w   = tid >> 6;          // wave 0..7 (unit nibble)
    const int l   = tid & 63;
    const int g   = blockIdx.x >> 4;   // batch group 0..3
    const int s   = blockIdx.x & 15;   // hidden slice 0..15 (32 units each)
    const int n   = l & 15;            // A-tile row (u-major: u=n>>2, gate=n&3)
    const int q   = l >> 4;            // quad (k-block; also: unit in epilogue)
    const int j   = s * 32 + w * 4 + q;// hidden unit owned in epilogue
    // weight row for the A-operand, tile rows ordered unit-major:
    // tile-row n -> global row = (n&3)*HID + s*32 + w*4 + (n>>2)
    const int roww = (n & 3) * HID + s * 32 + w * 4 + (n >> 2);
    const int b0  = g * 16;
    const int wg  = s * 8 + w;         // producing-wave id in group, 0..127

    __shared__ u64_t hs[2][4096];              // staged h, dbuf (64 KB)
    __shared__ float projsh[8][16][32];        // projection partials (16 KB)

    // W_hi AND W_lo fragments in registers: 17 K-chunks each (A-operand)
    bf16x8 Bh[17], Bl[17];
    #pragma unroll
    for (int c = 0; c < 17; c++) {
        Bh[c] = *(const bf16x8*)(wh  + roww * KDIM + c * 32 + q * 8);
        Bl[c] = *(const bf16x8*)(wlo + roww * KDIM + c * 32 + q * 8);
    }

    // epilogue constants: lane (q,n) owns unit j, batch n -> 4 gate biases
    float bias4[4];
    #pragma unroll
    for (int r = 0; r < 4; r++) bias4[r] = bih[r * HID + j] + bhh[r * HID + j];
    const float cw = convw[j];
    float cst = 0.f;                   // c-state: one (unit, batch) per lane

    // staging mapping: packet p = k*512+tid (k=0..3) -> wg' = p>>4, m = p&15
    // wg' = k*32 + hi5 (hi5 = tid>>4); c = k*4 + (hi5>>3), q = (hi5>>1)&3,
    // d = hi5&1, n = m
    const int m16 = tid & 15;
    const int hi5 = tid >> 4;
    const int sq  = (hi5 >> 1) & 3, sd = hi5 & 1, sc0v = hi5 >> 3;

    __syncthreads();

    union frag { u64_t d[2]; bf16x8 v; };

    for (int t = 0; t < T_STEPS; t++) {
        frag Ax, Lx;
        // x fragment (B-operand: lane (q,n) = x[batch n][dims q*8..+8])
        {
            int xo = (t * 64 + b0 + n) * 32 + q * 8;
            Ax.v = *(const bf16x8*)(xh + xo);
            Lx.v = *(const bf16x8*)(xl + xo);
        }

        // ---- stage + poll-on-data: 4 coherent 16B loads, tag every word ----
        const char* srcB = hx + (size_t)(((t & 1) * 4 + g)) * 32768 + tid * 16;
        u32x4 hv[4];
        #pragma unroll
        for (int k = 0; k < 4; k++) hv[k] = cld16(srcB + k * 8192);
        waitvm0();
        if (t > 0) {
            const uint_t exp = ((uint_t)(((t - 1) >> 1) & 1)) << 16;
            for (;;) {
                bool ok = true;
                #pragma unroll
                for (int k = 0; k < 4; k++) {
                    if (((hv[k][0] & 0x10000u) != exp) ||
                        ((hv[k][1] & 0x10000u) != exp) ||
                        ((hv[k][2] & 0x10000u) != exp) ||
                        ((hv[k][3] & 0x10000u) != exp)) {
                        hv[k] = cld16(srcB + k * 8192);
                        ok = false;
                    }
                }
                if (ok) break;
                __builtin_amdgcn_s_sleep(1);   // backoff: decongest fabric
                waitvm0();
            }
        }
        // deinterleave dwords (hi,lo)x4 units -> hi x4, lo x4; into LDS dbuf
        {
            const int buf = t & 1;
            #pragma unroll
            for (int k = 0; k < 4; k++) {
                uint_t I0 = hv[k][0], I1 = hv[k][1];
                uint_t I2 = hv[k][2], I3 = hv[k][3];
                uint_t hA = __builtin_amdgcn_perm(I1, I0, 0x05040100u);
                uint_t hB = __builtin_amdgcn_perm(I3, I2, 0x05040100u);
                uint_t lA = __builtin_amdgcn_perm(I1, I0, 0x07060302u);
                uint_t lB = __builtin_amdgcn_perm(I3, I2, 0x07060302u);
                int c  = k * 4 + sc0v;
                int li = ((c * 4 + sq) * 16 + m16) * 2 + sd;
                hs[buf][li]        = (u64_t)hA | ((u64_t)hB << 32);
                hs[buf][li + 2048] = (u64_t)lA | ((u64_t)lB << 32);
            }
        }
        __syncthreads();   // the only per-step barrier

        // fragments from LDS (B-operand now; per-lane data identical to R13's
        // A-operand reads). W (A-operand) in VGPRs.
        const int buf = t & 1;
        f32x4 a0 = {0,0,0,0}, a1 = {0,0,0,0}, a2 = {0,0,0,0},
              a3 = {0,0,0,0}, a4 = {0,0,0,0}, a5 = {0,0,0,0};
        #pragma unroll
        for (int c = 0; c < 16; c++) {
            frag Ah, Al;
            int li = ((c * 4 + q) * 16 + n) * 2;
            Ah.v = *(const bf16x8*)&hs[buf][li];
            Al.v = *(const bf16x8*)&hs[buf][li + 2048];
            if (c & 1) {
                a1 = MFMA(Bh[c], Ah.v, a1);
                a3 = MFMA(Bl[c], Ah.v, a3);
                a5 = MFMA(Bh[c], Al.v, a5);
            } else {
                a0 = MFMA(Bh[c], Ah.v, a0);
                a2 = MFMA(Bl[c], Ah.v, a2);
                a4 = MFMA(Bh[c], Al.v, a4);
            }
        }
        {   // x chunk (c=16)
            a0 = MFMA(Bh[16], Ax.v, a0);
            a2 = MFMA(Bl[16], Ax.v, a2);
            a4 = MFMA(Bh[16], Lx.v, a4);
        }
        f32x4 D = (a0 + a1) + (a2 + a3) + (a4 + a5);

        // ---- lane-local epilogue: D[r] = gate r of (unit j, batch n) ----
        char* dstB = hx + (size_t)((((t + 1) & 1) * 4 + g) * 128 + wg) * 256;
        const uint_t tag32 = ((uint_t)((t >> 1) & 1)) << 16;
        float iv = act_gate(D[0] + bias4[0], 0);
        float fv = act_gate(D[1] + bias4[1], 0);
        float gv = act_gate(D[2] + bias4[2], 1);
        float ov = act_gate(D[3] + bias4[3], 0);
        float cc = fv * cst + iv * gv;
        cst = cc;
        float th = act_gate(cc, 1);
        float h  = ov * th;
        float pr = cw * h;
        {
            ushort_t hb = f2bf(h);
            uint_t hvp = (uint_t)hb;
            uint_t lvp = (uint_t)f2bf(h - bf2f(hb));
            uint_t word = (hvp | (lvp << 16)) & ~0x10000u;
            word |= tag32;                       // every word self-tagged
            // packet layout: wg*256 + batch*16 + unit*4 (identical to R13)
            cst4(dstB + n * 16 + q * 4, word);
        }
        // NO drain, NO flag: tagged data IS the publication.

        // projection partial (off critical path): sum over the wave's 4 units
        pr += __shfl_xor(pr, 16);
        pr += __shfl_xor(pr, 32);
        if (l < 16) projsh[w][l][t & 31] = pr;   // l==n when q==0
        if ((t & 31) == 31) {
            __syncthreads();
            // 512 entries (16 batches x 32 steps), one per thread
            int b = tid >> 5, tl = tid & 31;
            float v = ((projsh[0][b][tl] + projsh[1][b][tl]) +
                       (projsh[2][b][tl] + projsh[3][b][tl])) +
                      ((projsh[4][b][tl] + projsh[5][b][tl]) +
                       (projsh[6][b][tl] + projsh[7][b][tl]));
            float* dpt = part + (size_t)((g * 16 + s) * 16 + b) * 1024 + (t - 31);
            __builtin_nontemporal_store(v, dpt + tl);
            __syncthreads();
        }
    }
}

extern "C" void kernel_launch(void* const* d_in, const int* in_sizes, int n_in,
                              void* d_out, int out_size, void* d_ws, size_t ws_size,
                              hipStream_t stream) {
    const float* in  = (const float*)d_in[0];
    const float* Wih = (const float*)d_in[1];
    const float* Whh = (const float*)d_in[2];
    const float* bih = (const float*)d_in[3];
    const float* bhh = (const float*)d_in[4];
    const float* cvw = (const float*)d_in[5];
    const float* cvb = (const float*)d_in[6];
    float* out = (float*)d_out;

    char* ws = (char*)d_ws;
    ushort_t* wh  = (ushort_t*)ws; ws += (size_t)2048 * KDIM * 2;      // 2,228,224
    ushort_t* wl  = (ushort_t*)ws; ws += (size_t)2048 * KDIM * 2;
    ushort_t* xh  = (ushort_t*)ws; ws += (size_t)1024 * 64 * 32 * 2;   // 4,194,304
    ushort_t* xl  = (ushort_t*)ws; ws += (size_t)1024 * 64 * 32 * 2;
    char*     hx  = ws;            ws += (size_t)2 * 4 * 128 * 16 * 16;// 262,144
    float*    pp  = (float*)ws;    ws += (size_t)64 * 16 * 1024 * 4;   // 4,194,304
    // total ~17.3 MB of ws

    k_init<<<256, 256, 0, stream>>>((uint_t*)hx);
    k_wcat<<<2048, 256, 0, stream>>>(Wih, Whh, wh, wl);
    k_xbuf<<<512, 256, 0, stream>>>(in, xh, xl);
    k_lstm<<<NBLK, NTHR, 0, stream>>>(wh, wl, xh, xl, hx,
                                      bih, bhh, cvw, pp);
    k_reduce<<<256, 256, 0, stream>>>(pp, out, cvb);
}